// Round 2
// baseline (235.389 us; speedup 1.0000x reference)
//
#include <hip/hip_runtime.h>

// EMA chunked scan + inverse-gather broadcast for DeChunkLayer.
// x: (1, 16384, 1024) f32, p_selected: (16384,) f32, b: (1, 32768) i32
// out: (1, 32768, 1024) f32
//
// z_t = (1-p_t) z_{t-1} + p_t x_t  (p clipped to [1e-4, 1-1e-4])
// out[f] = z[t] for f in [pos[t], pos[t+1])
//
// R1: CHUNK 64->32 (512 blocks -> 2 blocks/CU, 8 waves/CU); batch-8 register
// prefetch in final_kernel (x, p, pos) so the serial EMA chain no longer
// serializes on one outstanding load; pos_kernel wave-shuffle scan (2 barriers).

#define DCH 1024
#define L_COMP 16384
#define L_FULL 32768
#define CHUNK 32
#define NCHUNK (L_COMP / CHUNK) // 512
#define EPSV 1e-4f

__device__ __forceinline__ float clipp(float p) {
    p = fmaxf(p, EPSV);
    p = fminf(p, 1.0f - EPSV);
    return p;
}

// ---- Kernel 0: boundary mask -> pos[] (positions of the 16384 ones, plus sentinel L_FULL)
__global__ __launch_bounds__(1024) void pos_kernel(const int* __restrict__ b, int* __restrict__ pos) {
    const int tid = threadIdx.x;
    const int lane = tid & 63;
    const int wave = tid >> 6;
    int vals[32];
    const int4* b4 = reinterpret_cast<const int4*>(b) + tid * 8;
#pragma unroll
    for (int j = 0; j < 8; ++j) {
        int4 v = b4[j];
        vals[4 * j + 0] = v.x; vals[4 * j + 1] = v.y;
        vals[4 * j + 2] = v.z; vals[4 * j + 3] = v.w;
    }
    int s = 0;
#pragma unroll
    for (int k = 0; k < 32; ++k) s += vals[k];
    // wave-inclusive shuffle scan (64 lanes)
    int scan = s;
#pragma unroll
    for (int off = 1; off < 64; off <<= 1) {
        int n = __shfl_up(scan, off, 64);
        if (lane >= off) scan += n;
    }
    __shared__ int wsum[16];
    __shared__ int woff[16];
    if (lane == 63) wsum[wave] = scan;
    __syncthreads();
    if (tid == 0) {
        int acc = 0;
#pragma unroll
        for (int w = 0; w < 16; ++w) { woff[w] = acc; acc += wsum[w]; }
    }
    __syncthreads();
    int idx = woff[wave] + (scan - s); // exclusive prefix of this thread
#pragma unroll
    for (int k = 0; k < 32; ++k) {
        if (vals[k]) pos[idx++] = tid * 32 + k;
    }
    if (tid == 0) pos[L_COMP] = L_FULL;
}

// ---- Kernel A: per-chunk local scan (zero init) -> B_c[d] and chunk decay product A_c
__global__ __launch_bounds__(256) void chunk_kernel(const float* __restrict__ x, const float* __restrict__ p,
                                                    float* __restrict__ Bbuf, float* __restrict__ Abuf) {
    const int c = blockIdx.x;
    const int tid = threadIdx.x;
    const float4* x4 = reinterpret_cast<const float4*>(x) + (size_t)c * CHUNK * (DCH / 4) + tid;
    float4 h = make_float4(0.f, 0.f, 0.f, 0.f);
    float aprod = 1.0f;
    const int base = c * CHUNK;
    for (int ib = 0; ib < CHUNK; ib += 8) {
        float4 xv[8];
        float pv[8];
#pragma unroll
        for (int j = 0; j < 8; ++j) {
            xv[j] = x4[(ib + j) * (DCH / 4)];
            pv[j] = clipp(p[base + ib + j]); // uniform -> scalar load
        }
#pragma unroll
        for (int j = 0; j < 8; ++j) {
            float a = 1.0f - pv[j];
            h.x = fmaf(a, h.x, pv[j] * xv[j].x);
            h.y = fmaf(a, h.y, pv[j] * xv[j].y);
            h.z = fmaf(a, h.z, pv[j] * xv[j].z);
            h.w = fmaf(a, h.w, pv[j] * xv[j].w);
            aprod *= a;
        }
    }
    reinterpret_cast<float4*>(Bbuf)[c * (DCH / 4) + tid] = h;
    if (tid == 0) Abuf[c] = aprod;
}

// ---- Kernel B: sequential inter-chunk scan per channel; Hbuf[c][d] = state BEFORE chunk c
#define BATCHB 32
__global__ __launch_bounds__(64) void interchunk_kernel(const float* __restrict__ Bbuf,
                                                        const float* __restrict__ Abuf,
                                                        float* __restrict__ Hbuf) {
    const int ch = blockIdx.x * 64 + threadIdx.x; // 16 blocks x 64 = 1024 channels
    float h = 0.f;
    for (int cb = 0; cb < NCHUNK; cb += BATCHB) {
        float bv[BATCHB];
        float av[BATCHB];
#pragma unroll
        for (int j = 0; j < BATCHB; ++j) {
            bv[j] = Bbuf[(cb + j) * DCH + ch];
            av[j] = Abuf[cb + j]; // uniform -> SGPR
        }
#pragma unroll
        for (int j = 0; j < BATCHB; ++j) {
            Hbuf[(cb + j) * DCH + ch] = h;
            h = fmaf(av[j], h, bv[j]);
        }
    }
}

// ---- Kernel C: re-scan chunk with true initial state, broadcast-write each row to its
//      output range [pos[t], pos[t+1]). Batch-8 register prefetch of x, p, pos.
__global__ __launch_bounds__(256) void final_kernel(const float* __restrict__ x, const float* __restrict__ p,
                                                    const float* __restrict__ Hbuf, const int* __restrict__ pos,
                                                    float* __restrict__ out) {
    const int c = blockIdx.x;
    const int tid = threadIdx.x;
    const float4* x4 = reinterpret_cast<const float4*>(x) + (size_t)c * CHUNK * (DCH / 4) + tid;
    float4* out4 = reinterpret_cast<float4*>(out) + tid;
    float4 h = reinterpret_cast<const float4*>(Hbuf)[c * (DCH / 4) + tid];
    const int base = c * CHUNK;
    int f0 = pos[base];
    for (int ib = 0; ib < CHUNK; ib += 8) {
        float4 xv[8];
        float pv[8];
        int fe[8];
#pragma unroll
        for (int j = 0; j < 8; ++j) {
            xv[j] = x4[(ib + j) * (DCH / 4)];
            pv[j] = clipp(p[base + ib + j]);  // uniform -> scalar
            fe[j] = pos[base + ib + j + 1];   // uniform -> scalar
        }
#pragma unroll
        for (int j = 0; j < 8; ++j) {
            float a = 1.0f - pv[j];
            h.x = fmaf(a, h.x, pv[j] * xv[j].x);
            h.y = fmaf(a, h.y, pv[j] * xv[j].y);
            h.z = fmaf(a, h.z, pv[j] * xv[j].z);
            h.w = fmaf(a, h.w, pv[j] * xv[j].w);
            for (int f = f0; f < fe[j]; ++f) {
                out4[(size_t)f * (DCH / 4)] = h;
            }
            f0 = fe[j];
        }
    }
}

extern "C" void kernel_launch(void* const* d_in, const int* in_sizes, int n_in,
                              void* d_out, int out_size, void* d_ws, size_t ws_size,
                              hipStream_t stream) {
    const float* x = (const float*)d_in[0];
    const float* p = (const float*)d_in[1];
    const int* b = (const int*)d_in[2];
    float* out = (float*)d_out;

    char* ws = (char*)d_ws;
    float* Abuf = (float*)ws;                       // NCHUNK floats (2 KiB)
    int* pos = (int*)(ws + 4096);                   // (L_COMP+1) ints (~64 KiB)
    float* Bbuf = (float*)(ws + 4096 + 69632);      // NCHUNK*DCH floats (2 MiB), 16B aligned
    float* Hbuf = Bbuf + (size_t)NCHUNK * DCH;      // NCHUNK*DCH floats (2 MiB)

    pos_kernel<<<1, 1024, 0, stream>>>(b, pos);
    chunk_kernel<<<NCHUNK, 256, 0, stream>>>(x, p, Bbuf, Abuf);
    interchunk_kernel<<<16, 64, 0, stream>>>(Bbuf, Abuf, Hbuf);
    final_kernel<<<NCHUNK, 256, 0, stream>>>(x, p, Hbuf, pos, out);
}

// Round 4
// 226.140 us; speedup vs baseline: 1.0409x; 1.0409x over previous
//
#include <hip/hip_runtime.h>

// EMA chunked scan + inverse-gather broadcast for DeChunkLayer — 2 plain
// kernels, no cooperative launch (R3: coop launch failed in this harness).
//
// x: (1, 16384, 1024) f32, p_selected: (16384,) f32, b: (1, 32768) i32
// out: (1, 32768, 1024) f32
// z_t = (1-p_t) z_{t-1} + p_t x_t  (p clipped to [1e-4, 1-1e-4])
// out[f] = z[t] for f in [pos[t], pos[t+1])
//
// K1: per-chunk local scan -> Bbuf/Abuf; per-segment b popcount -> bsum.
// K2: per-block redundant interchunk replay (<=511 serial steps off L2-resident
//     Bbuf) + rank-select of this chunk's 33 pos values + final scan + ranged
//     broadcast writes. All inter-block dataflow crosses ONE kernel boundary.

#define DCH 1024
#define L_COMP 16384
#define L_FULL 32768
#define CHUNK 32
#define NCHUNK (L_COMP / CHUNK)   // 512
#define SEG (L_FULL / NCHUNK)     // 64 b-elements per block
#define EPSV 1e-4f

__device__ __forceinline__ float clipp(float p) {
    p = fmaxf(p, EPSV);
    p = fminf(p, 1.0f - EPSV);
    return p;
}

// ---- K1: chunk-local scan (zero init) -> Bbuf[c], Abuf[c]; b segment sums
__global__ __launch_bounds__(256, 2) void chunk_kernel(
    const float* __restrict__ x, const float* __restrict__ p,
    const int* __restrict__ b,
    float* __restrict__ Bbuf, float* __restrict__ Abuf, int* __restrict__ bsum) {
    const int c = blockIdx.x;
    const int tid = threadIdx.x;
    const int lane = tid & 63;
    const int wave = tid >> 6;
    const int base = c * CHUNK;

    const float4* x4 = reinterpret_cast<const float4*>(x) + (size_t)c * CHUNK * (DCH / 4) + tid;
    float4 h = make_float4(0.f, 0.f, 0.f, 0.f);
    float aprod = 1.0f;
    for (int ib = 0; ib < CHUNK; ib += 8) {
        float4 xv[8];
        float pv[8];
#pragma unroll
        for (int j = 0; j < 8; ++j) {
            xv[j] = x4[(ib + j) * (DCH / 4)];
            pv[j] = clipp(p[base + ib + j]); // uniform -> scalar load
        }
#pragma unroll
        for (int j = 0; j < 8; ++j) {
            float a = 1.0f - pv[j];
            h.x = fmaf(a, h.x, pv[j] * xv[j].x);
            h.y = fmaf(a, h.y, pv[j] * xv[j].y);
            h.z = fmaf(a, h.z, pv[j] * xv[j].z);
            h.w = fmaf(a, h.w, pv[j] * xv[j].w);
            aprod *= a;
        }
    }
    reinterpret_cast<float4*>(Bbuf)[c * (DCH / 4) + tid] = h;
    if (tid == 0) Abuf[c] = aprod;
    if (wave == 0) {
        int v = b[c * SEG + lane];
        int s = v;
#pragma unroll
        for (int off = 1; off < 64; off <<= 1) s += __shfl_xor(s, off, 64);
        if (lane == 0) bsum[c] = s;
    }
}

// ---- K2: bpref scan + rank-select pos + redundant interchunk + final scan/write
__global__ __launch_bounds__(256, 2) void dechunk_kernel(
    const float* __restrict__ x, const float* __restrict__ p,
    const int* __restrict__ b, float* __restrict__ out,
    const float* __restrict__ Bbuf, const float* __restrict__ Abuf,
    const int* __restrict__ bsum) {
    const int c = blockIdx.x;
    const int tid = threadIdx.x;
    const int lane = tid & 63;
    const int wave = tid >> 6;
    const int base = c * CHUNK;

    __shared__ int bpref[NCHUNK + 1];
    __shared__ int spos[CHUNK + 1];
    __shared__ int wtot[4];

    // (a) block-local exclusive prefix over the 512 segment sums
    {
        int v0 = bsum[2 * tid];
        int v1 = bsum[2 * tid + 1];
        int s = v0 + v1;
        int incl = s;
#pragma unroll
        for (int off = 1; off < 64; off <<= 1) {
            int n = __shfl_up(incl, off, 64);
            if (lane >= off) incl += n;
        }
        if (lane == 63) wtot[wave] = incl;
        __syncthreads();
        int woff = 0;
        for (int w = 0; w < wave; ++w) woff += wtot[w];
        int ex = woff + incl - s; // exclusive prefix of this thread's pair
        bpref[2 * tid] = ex;
        bpref[2 * tid + 1] = ex + v0;
        if (tid == 0) bpref[NCHUNK] = L_COMP;
        __syncthreads();
    }

    // (b) rank-select this chunk's 33 pos values (threads 0..32)
    if (tid <= CHUNK) {
        int t = base + tid; // global one-rank (0-indexed)
        int posv = L_FULL;
        if (t < L_COMP) {
            int lo = 0, hi = NCHUNK;
            while (hi - lo > 1) {
                int mid = (lo + hi) >> 1;
                if (bpref[mid] <= t) lo = mid; else hi = mid;
            }
            int lr = t - bpref[lo]; // local rank within segment lo
            const int4* bseg = reinterpret_cast<const int4*>(b) + lo * (SEG / 4);
            int cnt = 0;
#pragma unroll 4
            for (int q = 0; q < SEG / 4; ++q) {
                int4 w = bseg[q];
                if (w.x) { if (cnt == lr) posv = lo * SEG + 4 * q + 0; ++cnt; }
                if (w.y) { if (cnt == lr) posv = lo * SEG + 4 * q + 1; ++cnt; }
                if (w.z) { if (cnt == lr) posv = lo * SEG + 4 * q + 2; ++cnt; }
                if (w.w) { if (cnt == lr) posv = lo * SEG + 4 * q + 3; ++cnt; }
            }
        }
        spos[tid] = posv;
    }

    // (c) redundant interchunk replay: h = state before chunk c (4 channels/thread)
    float4 h = make_float4(0.f, 0.f, 0.f, 0.f);
    {
        const float4* B4 = reinterpret_cast<const float4*>(Bbuf) + tid;
        int k = 0;
        for (; k + 16 <= c; k += 16) {
            float4 bv[16];
            float av[16];
#pragma unroll
            for (int j = 0; j < 16; ++j) {
                bv[j] = B4[(k + j) * (DCH / 4)];
                av[j] = Abuf[k + j]; // uniform -> scalar load
            }
#pragma unroll
            for (int j = 0; j < 16; ++j) {
                h.x = fmaf(av[j], h.x, bv[j].x);
                h.y = fmaf(av[j], h.y, bv[j].y);
                h.z = fmaf(av[j], h.z, bv[j].z);
                h.w = fmaf(av[j], h.w, bv[j].w);
            }
        }
        for (; k < c; ++k) {
            float4 bv = B4[k * (DCH / 4)];
            float a = Abuf[k];
            h.x = fmaf(a, h.x, bv.x);
            h.y = fmaf(a, h.y, bv.y);
            h.z = fmaf(a, h.z, bv.z);
            h.w = fmaf(a, h.w, bv.w);
        }
    }
    __syncthreads();

    // (d) final scan of chunk c with true init; broadcast-write output ranges
    {
        const float4* x4 = reinterpret_cast<const float4*>(x) + (size_t)c * CHUNK * (DCH / 4) + tid;
        float4* out4 = reinterpret_cast<float4*>(out) + tid;
        int f0 = spos[0];
        for (int ib = 0; ib < CHUNK; ib += 8) {
            float4 xv[8];
            float pv[8];
            int fe[8];
#pragma unroll
            for (int j = 0; j < 8; ++j) {
                xv[j] = x4[(ib + j) * (DCH / 4)];
                pv[j] = clipp(p[base + ib + j]); // uniform -> scalar
                fe[j] = spos[ib + j + 1];        // LDS
            }
#pragma unroll
            for (int j = 0; j < 8; ++j) {
                float a = 1.0f - pv[j];
                h.x = fmaf(a, h.x, pv[j] * xv[j].x);
                h.y = fmaf(a, h.y, pv[j] * xv[j].y);
                h.z = fmaf(a, h.z, pv[j] * xv[j].z);
                h.w = fmaf(a, h.w, pv[j] * xv[j].w);
                for (int f = f0; f < fe[j]; ++f) {
                    out4[(size_t)f * (DCH / 4)] = h;
                }
                f0 = fe[j];
            }
        }
    }
}

extern "C" void kernel_launch(void* const* d_in, const int* in_sizes, int n_in,
                              void* d_out, int out_size, void* d_ws, size_t ws_size,
                              hipStream_t stream) {
    const float* x = (const float*)d_in[0];
    const float* p = (const float*)d_in[1];
    const int* b = (const int*)d_in[2];
    float* out = (float*)d_out;

    char* ws = (char*)d_ws;
    float* Abuf = (float*)ws;                  // NCHUNK floats (2 KiB)
    int* bsum = (int*)(ws + 4096);             // NCHUNK ints (2 KiB)
    float* Bbuf = (float*)(ws + 8192);         // NCHUNK*DCH floats (2 MiB), 16B aligned

    chunk_kernel<<<NCHUNK, 256, 0, stream>>>(x, p, b, Bbuf, Abuf, bsum);
    dechunk_kernel<<<NCHUNK, 256, 0, stream>>>(x, p, b, out, Bbuf, Abuf, bsum);
}